// Round 3
// baseline (137.238 us; speedup 1.0000x reference)
//
#include <hip/hip_runtime.h>

// VOCAB=1e6, DIM=64, BAGS=16384, N_IDX=819200, CAT_DIM=128.
// Output row = [eb(64) | eb(64) | cat(128)] = 256 f32.
//
// R3: 16-lane sub-waves, int4 (16B) row loads -> one wave instruction gathers
// 4 full 256B rows concurrently (4x MLP vs R2's 1 row / instruction).
// 819200 = 32768 subchunks x 25 indices; 2048 blocks x 256 thr = 32768 sub-waves.
// Uniform 25-iteration gather loop (no masked waste); divergence only at the
// rare bag-boundary flush.

constexpr int SUBCHUNK = 25;

__global__ __launch_bounds__(256) void init_out_kernel(
    const float* __restrict__ cat, float* __restrict__ out, int total)
{
    int t = blockIdx.x * 256 + threadIdx.x;   // total = num_bags*256
    if (t >= total) return;
    int b = t >> 8, c = t & 255;
    out[t] = (c < 128) ? 0.0f : cat[(b << 7) + (c - 128)];
}

__global__ __launch_bounds__(256) void embag_kernel(
    const int* __restrict__ wq,             // [VOCAB, 64] int32 codes
    const float* __restrict__ scales,       // [VOCAB]
    const float* __restrict__ biases,       // [VOCAB]
    const unsigned int* __restrict__ idx32, // indices viewed as u32 words
    const unsigned int* __restrict__ off32, // offsets viewed as u32 words
    float* __restrict__ out,                // [BAGS, 256]
    int num_bags, int n_idx)
{
    // int64 vs int32 layout detection (LE): high words of first indices == 0.
    const bool is64 = ((idx32[1] | idx32[3] | idx32[5] | idx32[7]) == 0u);
    const int sh = is64 ? 1 : 0;

    const int sub = (blockIdx.x * 256 + threadIdx.x) >> 4;  // global sub-wave id
    const int sl  = threadIdx.x & 15;                       // lane in sub-wave
    const long long base = (long long)sub * SUBCHUNK;
    if (base >= n_idx) return;
    const int i0  = (int)base;
    const int cnt = min(SUBCHUNK, n_idx - i0);

    // smallest b with off[b+1] > i0 (searchsorted-right semantics)
    int lo = 0, hi = num_bags - 1;
    while (lo < hi) {
        int mid = (lo + hi) >> 1;
        if ((int)off32[(unsigned)(mid + 1) << sh] > i0) hi = mid; else lo = mid + 1;
    }
    int b = lo;
    int bend = (int)off32[(unsigned)(b + 1) << sh];

    float a0 = 0.f, a1 = 0.f, a2 = 0.f, a3 = 0.f, ab = 0.f;

    #pragma unroll 5
    for (int k = 0; k < cnt; ++k) {
        const int j = i0 + k;
        while (j >= bend) {
            // flush partial for bag b (rare; diverges per sub-wave)
            float* p = out + ((long long)b << 8) + (sl << 2);
            const float v0 = a0 + ab, v1 = a1 + ab, v2 = a2 + ab, v3 = a3 + ab;
            atomicAdd(p + 0, v0);  atomicAdd(p + 1, v1);
            atomicAdd(p + 2, v2);  atomicAdd(p + 3, v3);
            atomicAdd(p + 64, v0); atomicAdd(p + 65, v1);
            atomicAdd(p + 66, v2); atomicAdd(p + 67, v3);
            a0 = a1 = a2 = a3 = ab = 0.f;
            ++b;
            bend = (int)off32[(unsigned)(b + 1) << sh];
        }
        const int idx = (int)idx32[(unsigned)j << sh];      // broadcast in sub-wave
        const float s  = scales[idx];
        const float bi = biases[idx];
        const int4 q = *reinterpret_cast<const int4*>(wq + idx * 64 + (sl << 2));
        a0 = fmaf((float)q.x, s, a0);
        a1 = fmaf((float)q.y, s, a1);
        a2 = fmaf((float)q.z, s, a2);
        a3 = fmaf((float)q.w, s, a3);
        ab += bi;
    }

    // final flush
    float* p = out + ((long long)b << 8) + (sl << 2);
    const float v0 = a0 + ab, v1 = a1 + ab, v2 = a2 + ab, v3 = a3 + ab;
    atomicAdd(p + 0, v0);  atomicAdd(p + 1, v1);
    atomicAdd(p + 2, v2);  atomicAdd(p + 3, v3);
    atomicAdd(p + 64, v0); atomicAdd(p + 65, v1);
    atomicAdd(p + 66, v2); atomicAdd(p + 67, v3);
}

extern "C" void kernel_launch(void* const* d_in, const int* in_sizes, int n_in,
                              void* d_out, int out_size, void* d_ws, size_t ws_size,
                              hipStream_t stream) {
    const int*          wq     = (const int*)d_in[0];
    const float*        scales = (const float*)d_in[1];
    const float*        biases = (const float*)d_in[2];
    const unsigned int* idx32  = (const unsigned int*)d_in[3];
    const unsigned int* off32  = (const unsigned int*)d_in[4];
    const float*        cat    = (const float*)d_in[5];
    float*              out    = (float*)d_out;

    const int num_bags = in_sizes[5] / 128;       // 16384
    const int n_idx    = in_sizes[3];             // 819200

    const int total = num_bags * 256;
    init_out_kernel<<<(total + 255) / 256, 256, 0, stream>>>(cat, out, total);

    const int nsub   = (n_idx + SUBCHUNK - 1) / SUBCHUNK;  // 32768
    const int blocks = (nsub * 16 + 255) / 256;            // 2048
    embag_kernel<<<blocks, 256, 0, stream>>>(
        wq, scales, biases, idx32, off32, out, num_bags, n_idx);
}

// Round 4
// 70.089 us; speedup vs baseline: 1.9581x; 1.9581x over previous
//
#include <hip/hip_runtime.h>

// VOCAB=1e6, DIM=64, BAGS=16384, N_IDX=819200, CAT_DIM=128.
// Output row = [eb(64) | eb(64) | cat(128)] = 256 f32.
//
// R4: wave-per-chunk (CHUNK=50, 819200=16384*50 -> perfect balance, 4096 blocks).
// Phase 1: per-lane prefetch of idx/scale/bias for the whole chunk (3 loads).
// Phase 2: burst-issue 25 independent 256B row gathers via readlane->SGPR
//          addressing (deep MLP, no dependent scalar loads in the chain).
// Phase 3: unrolled consume; scale/bias broadcast via readlane (VALU only);
//          wave-coalesced 256B atomics at bag boundaries (R3's scalar-atomic
//          explosion reverted).

constexpr int CHUNK = 50;
constexpr int GROUP = 25;

__device__ __forceinline__ float readlane_f(float x, int k) {
    return __int_as_float(__builtin_amdgcn_readlane(__float_as_int(x), k));
}

__global__ __launch_bounds__(256) void init_out_kernel(
    const float* __restrict__ cat, float* __restrict__ out, int total)
{
    int t = blockIdx.x * 256 + threadIdx.x;   // total = num_bags*256
    if (t >= total) return;
    int b = t >> 8, c = t & 255;
    out[t] = (c < 128) ? 0.0f : cat[(b << 7) + (c - 128)];
}

__global__ __launch_bounds__(256) void embag_kernel(
    const int* __restrict__ wq,             // [VOCAB, 64] int32 codes
    const float* __restrict__ scales,       // [VOCAB]
    const float* __restrict__ biases,       // [VOCAB]
    const unsigned int* __restrict__ idx32, // indices viewed as u32 words
    const unsigned int* __restrict__ off32, // offsets viewed as u32 words
    float* __restrict__ out,                // [BAGS, 256]
    int num_bags, int n_idx)
{
    // int64 vs int32 layout detection (LE): high words of first indices == 0.
    const bool is64 = ((idx32[1] | idx32[3] | idx32[5] | idx32[7]) == 0u);
    const int sh = is64 ? 1 : 0;

    const int lane = threadIdx.x & 63;
    const int wid  = blockIdx.x * 4 + (threadIdx.x >> 6);
    const long long base = (long long)wid * CHUNK;
    if (base >= n_idx) return;
    const int i0  = (int)base;
    const int cnt = min(CHUNK, n_idx - i0);

    // Phase 1: per-lane prefetch (lanes >= cnt clamp to last valid -> safe dup)
    const int li = i0 + min(lane, cnt - 1);
    const int myidx = (int)idx32[(unsigned)li << sh];
    const float mys = scales[myidx];
    const float myb = biases[myidx];

    // start bag: smallest b with off[b+1] > i0 (searchsorted-right semantics)
    int lo = 0, hi = num_bags - 1;
    while (lo < hi) {
        int mid = (lo + hi) >> 1;
        if ((int)off32[(unsigned)(mid + 1) << sh] > i0) hi = mid; else lo = mid + 1;
    }
    int b = lo;
    int bend = (int)off32[(unsigned)(b + 1) << sh];

    float acc = 0.f, ab = 0.f;
    const char* wqb = (const char*)wq + (lane << 2);

    for (int g = 0; g < CHUNK; g += GROUP) {
        // Phase 2: burst-issue GROUP independent row loads
        int q[GROUP];
        #pragma unroll
        for (int k = 0; k < GROUP; ++k) {
            const int ik = __builtin_amdgcn_readlane(myidx, g + k); // SGPR
            q[k] = *(const int*)(wqb + ((long long)ik << 8));       // 256B/wave
        }
        // Phase 3: consume with boundary flushes
        #pragma unroll
        for (int k = 0; k < GROUP; ++k) {
            const int j = i0 + g + k;
            if (j >= n_idx) break;
            if (j >= bend) {
                const float v = acc + ab;
                float* p = out + ((long long)b << 8) + lane;
                atomicAdd(p, v);        // eb1
                atomicAdd(p + 64, v);   // eb2 (identical sum)
                acc = 0.f; ab = 0.f;
                do { ++b; bend = (int)off32[(unsigned)(b + 1) << sh]; } while (bend <= j);
            }
            acc = fmaf((float)q[k], readlane_f(mys, g + k), acc);
            ab += readlane_f(myb, g + k);
        }
    }

    // final flush
    const float v = acc + ab;
    float* p = out + ((long long)b << 8) + lane;
    atomicAdd(p, v);
    atomicAdd(p + 64, v);
}

extern "C" void kernel_launch(void* const* d_in, const int* in_sizes, int n_in,
                              void* d_out, int out_size, void* d_ws, size_t ws_size,
                              hipStream_t stream) {
    const int*          wq     = (const int*)d_in[0];
    const float*        scales = (const float*)d_in[1];
    const float*        biases = (const float*)d_in[2];
    const unsigned int* idx32  = (const unsigned int*)d_in[3];
    const unsigned int* off32  = (const unsigned int*)d_in[4];
    const float*        cat    = (const float*)d_in[5];
    float*              out    = (float*)d_out;

    const int num_bags = in_sizes[5] / 128;       // 16384
    const int n_idx    = in_sizes[3];             // 819200

    const int total = num_bags * 256;
    init_out_kernel<<<(total + 255) / 256, 256, 0, stream>>>(cat, out, total);

    const int nchunks = (n_idx + CHUNK - 1) / CHUNK;   // 16384 waves
    const int blocks  = (nchunks + 3) / 4;             // 4096
    embag_kernel<<<blocks, 256, 0, stream>>>(
        wq, scales, biases, idx32, off32, out, num_bags, n_idx);
}